// Round 2
// baseline (5408.198 us; speedup 1.0000x reference)
//
#include <hip/hip_runtime.h>
#include <hip/hip_bf16.h>
#include <math.h>

// Problem constants (from reference setup_inputs; fixed).
#define HIDDEN 1024
#define MEL    80
#define TSTEPS 1000
#define BATCH  64

// Recurrence kernel geometry.
#define NBLK 64                 // persistent blocks (1 per CU region; 64 << 256 CUs -> co-resident)
#define TPB  512                // 8 waves
#define JPB  (HIDDEN / NBLK)    // 16 hidden units owned per block
#define ROWS (4 * JPB)          // 64 gate-rows per block (i,f,g,o)
#define CPT  (HIDDEN / 8)       // 128 columns per thread (8 threads per row)

__device__ __forceinline__ float sigm(float x) { return 1.0f / (1.0f + expf(-x)); }

__global__ void init_bar(unsigned* bar) { *bar = 0u; }

// Device-scope sense-free barrier: monotonic counter, target = step * NBLK.
__device__ __forceinline__ void grid_barrier(unsigned* bar, unsigned target) {
    __syncthreads();
    if (threadIdx.x == 0) {
        __threadfence();  // release: publish this block's h-slice stores (agent scope)
        __hip_atomic_fetch_add(bar, 1u, __ATOMIC_RELAXED, __HIP_MEMORY_SCOPE_AGENT);
        while (__hip_atomic_load(bar, __ATOMIC_ACQUIRE, __HIP_MEMORY_SCOPE_AGENT) < target) {
        }
    }
    __syncthreads();
}

// Persistent decoder recurrence. Weights folded (W_comb = Whh + Wih@lin_W) and
// held in registers in fp32; only h (4KB) crosses global memory per step.
// All inputs are fp32 (reference dtypes are jnp.float32).
__global__ __launch_bounds__(TPB, 2) void tts_recur(
    const float* __restrict__ dec_Wih,   // [4096, 80]
    const float* __restrict__ dec_Whh,   // [4096, 1024]
    const float* __restrict__ dec_bih,   // [4096]
    const float* __restrict__ dec_bhh,   // [4096]
    const float* __restrict__ lin_W,     // [80, 1024]
    const float* __restrict__ lin_b,     // [80]
    float* __restrict__ h_hist,          // [TSTEPS, 1024] (workspace)
    unsigned* __restrict__ bar)
{
    const int tid  = threadIdx.x;
    const int blk  = blockIdx.x;
    const int r    = tid >> 3;          // local gate-row 0..63
    const int c8   = tid & 7;           // column chunk 0..7
    const int gate = r >> 4;            // 0..3 (i,f,g,o)
    const int jj   = r & (JPB - 1);     // 0..15
    const int row_g = gate * HIDDEN + blk * JPB + jj;   // global row in [0,4096)

    __shared__ __align__(16) float h_s[HIDDEN];
    __shared__ float g_s[ROWS];
    __shared__ float c_s[JPB];

    // ---- one-time: build folded weight slice in registers (fp32) ----
    // w[k] holds float4 at column index (k+c8)&31 within this thread's 128-col
    // chunk; the rotation makes the per-step LDS reads cover all 32 banks.
    const float* wih = dec_Wih + (size_t)row_g * MEL;     // 320B rows, 16B aligned
    const float* whh = dec_Whh + (size_t)row_g * HIDDEN;  // 4KB rows, 16B aligned
    float4 w[32];
#pragma unroll
    for (int k = 0; k < 32; ++k) {
        const int c4  = (k + c8) & 31;
        const int col = c8 * CPT + c4 * 4;
        float4 a = *(const float4*)(whh + col);
        for (int m = 0; m < MEL; ++m) {
            const float aw = wih[m];
            const float4 lw = *(const float4*)(lin_W + (size_t)m * HIDDEN + col);
            a.x = fmaf(aw, lw.x, a.x);
            a.y = fmaf(aw, lw.y, a.y);
            a.z = fmaf(aw, lw.z, a.z);
            a.w = fmaf(aw, lw.w, a.w);
        }
        w[k] = a;
    }
    // Biases: b_dec for step 0 (x=0 -> no lin_b fold), b_comb for steps >= 1.
    const float b_dec_r = dec_bih[row_g] + dec_bhh[row_g];
    float b_comb_r = b_dec_r;
    for (int m = 0; m < MEL; ++m)
        b_comb_r = fmaf(wih[m], lin_b[m], b_comb_r);

    // ---- step 0: g = b_dec (h=c=x=0) ----
    if (c8 == 0) g_s[r] = b_dec_r;
    __syncthreads();
    if (tid < JPB) {
        const float gi = g_s[tid], gg = g_s[2 * JPB + tid], go = g_s[3 * JPB + tid];
        const float c = sigm(gi) * tanhf(gg);   // f-gate * c0 = 0
        const float h = sigm(go) * tanhf(c);
        c_s[tid] = c;
        h_hist[blk * JPB + tid] = h;
    }

    // ---- steps 1..TSTEPS-1 ----
    const float4* hs4 = ((const float4*)h_s) + c8 * 32;
    for (int t = 1; t < TSTEPS; ++t) {
        grid_barrier(bar, (unsigned)t * NBLK);          // all blocks published h[t-1]

        if (tid < 256) {                                // stage h[t-1] -> LDS (4KB)
            ((float4*)h_s)[tid] = ((const float4*)(h_hist + (size_t)(t - 1) * HIDDEN))[tid];
        }
        __syncthreads();

        float acc = 0.0f;
#pragma unroll
        for (int k = 0; k < 32; ++k) {
            const float4 hv = hs4[(k + c8) & 31];       // bank-conflict-free rotation
            acc = fmaf(w[k].x, hv.x, acc);
            acc = fmaf(w[k].y, hv.y, acc);
            acc = fmaf(w[k].z, hv.z, acc);
            acc = fmaf(w[k].w, hv.w, acc);
        }
        acc += __shfl_down(acc, 4, 8);
        acc += __shfl_down(acc, 2, 8);
        acc += __shfl_down(acc, 1, 8);
        if (c8 == 0) g_s[r] = acc + b_comb_r;
        __syncthreads();

        if (tid < JPB) {
            const float gi = g_s[tid], gf = g_s[JPB + tid], gg = g_s[2 * JPB + tid], go = g_s[3 * JPB + tid];
            const float c = sigm(gf) * c_s[tid] + sigm(gi) * tanhf(gg);
            const float h = sigm(go) * tanhf(c);
            c_s[tid] = c;
            h_hist[(size_t)t * HIDDEN + blk * JPB + tid] = h;
        }
        // next grid_barrier's entry __syncthreads orders these writes before arrive
    }
}

// Epilogue: frame[t] = lin_W @ h[t] + lin_b, broadcast to all 64 batch rows.
__global__ __launch_bounds__(128) void tts_frames(
    const float* __restrict__ lin_W, const float* __restrict__ lin_b,
    const float* __restrict__ h_hist, float* __restrict__ out)
{
    const int t = blockIdx.x;
    const int tid = threadIdx.x;
    __shared__ __align__(16) float h_s[HIDDEN];
    const float4* src = (const float4*)(h_hist + (size_t)t * HIDDEN);
    ((float4*)h_s)[tid] = src[tid];
    ((float4*)h_s)[tid + 128] = src[tid + 128];
    __syncthreads();
    if (tid < MEL) {
        const float* wrow = lin_W + (size_t)tid * HIDDEN;
        float acc = lin_b[tid];
#pragma unroll 8
        for (int c = 0; c < HIDDEN; ++c)
            acc = fmaf(wrow[c], h_s[c], acc);
        const size_t o = (size_t)t * MEL + tid;
        for (int b = 0; b < BATCH; ++b)
            out[o + (size_t)b * TSTEPS * MEL] = acc;
    }
}

extern "C" void kernel_launch(void* const* d_in, const int* in_sizes, int n_in,
                              void* d_out, int out_size, void* d_ws, size_t ws_size,
                              hipStream_t stream) {
    // setup_inputs order: 0 text, 1 text_lens, 2 max_audio_len, 3 W_emb,
    // 4..7 enc_{Wih,Whh,bih,bhh}, 8..11 dec_{Wih,Whh,bih,bhh}, 12 lin_W, 13 lin_b.
    // Encoder inputs (0..7) are dead code in the reference output -> unused.
    const float* dec_Wih = (const float*)d_in[8];
    const float* dec_Whh = (const float*)d_in[9];
    const float* dec_bih = (const float*)d_in[10];
    const float* dec_bhh = (const float*)d_in[11];
    const float* lin_W   = (const float*)d_in[12];
    const float* lin_b   = (const float*)d_in[13];
    float* out = (float*)d_out;

    // Workspace: h_hist fp32 [1000,1024] (4.096 MB) + barrier counter.
    float* h_hist = (float*)d_ws;
    unsigned* bar = (unsigned*)((char*)d_ws + (size_t)TSTEPS * HIDDEN * sizeof(float));

    hipLaunchKernelGGL(init_bar, dim3(1), dim3(1), 0, stream, bar);
    hipLaunchKernelGGL(tts_recur, dim3(NBLK), dim3(TPB), 0, stream,
                       dec_Wih, dec_Whh, dec_bih, dec_bhh, lin_W, lin_b, h_hist, bar);
    hipLaunchKernelGGL(tts_frames, dim3(TSTEPS), dim3(128), 0, stream,
                       lin_W, lin_b, h_hist, out);
}